// Round 5
// baseline (354.385 us; speedup 1.0000x reference)
//
#include <hip/hip_runtime.h>
#include <math.h>

namespace {
constexpr int BATCH = 4;
constexpr int DDIM  = 128;
constexpr int HDIM  = 192;
constexpr int WDIM  = 192;
constexpr long long NTOT = (long long)BATCH * DDIM * HDIM * WDIM; // 18,874,368
constexpr int NDSC  = 4 * 1 * 8 * 12 * 12;                        // 4608

constexpr int DT     = 8;               // d planes per block
constexpr int NDC    = DDIM / DT;       // 16
constexpr int HB     = 16;              // h rows per block (4 waves x 4 rows)
constexpr int NHB    = HDIM / HB;       // 12
constexpr int BLOCKV = 256;             // 4 waves
constexpr int GRIDV  = BATCH * NDC * NHB; // 768 = exactly 3 blocks/CU
constexpr int PLSTR  = HDIM * WDIM;     // 36,864 floats per plane
constexpr int BLOCKF = 256;
}

// gd contribution: (|dy|*s - |dp|*s)^2 == s^2 * (|dy|-|dp|)^2, s2 in {1, 0.25}
#define GTERM(dy, dp, s2) { float t0_ = fabsf(dy) - fabsf(dp); gd = fmaf(t0_ * t0_, (s2), gd); }

// 12 contiguous floats via 3 dwordx4 from ONE address (asm: cannot be sunk by
// the compiler -> loads stay in flight until the explicit vmcnt drain).
#define ALOAD3(d0_, d1_, d2_, ap_)                                   \
    asm volatile("global_load_dwordx4 %0, %3, off\n\t"               \
                 "global_load_dwordx4 %1, %3, off offset:16\n\t"     \
                 "global_load_dwordx4 %2, %3, off offset:32"         \
                 : "=&v"(d0_), "=&v"(d1_), "=&v"(d2_)                \
                 : "v"((const void*)(ap_)))

__device__ __forceinline__ float4 shup16(float4 v) {
    float4 r;
    r.x = __shfl_up(v.x, 16, 64); r.y = __shfl_up(v.y, 16, 64);
    r.z = __shfl_up(v.z, 16, 64); r.w = __shfl_up(v.w, 16, 64);
    return r;
}
__device__ __forceinline__ float4 shdn16(float4 v) {
    float4 r;
    r.x = __shfl_down(v.x, 16, 64); r.y = __shfl_down(v.y, 16, 64);
    r.z = __shfl_down(v.z, 16, 64); r.w = __shfl_down(v.w, 16, 64);
    return r;
}
__device__ __forceinline__ float4 sel4(bool c, float4 a, float4 b) {
    float4 r;
    r.x = c ? a.x : b.x; r.y = c ? a.y : b.y;
    r.z = c ? a.z : b.z; r.w = c ? a.w : b.w;
    return r;
}

// Register-only stencil: wave = 4 h-rows x 16 w-strips(12 floats). H-neighbors
// come from other lanes' center registers (__shfl +/-16); W-edges from
// __shfl +/-1; D from a register pipeline. Only the 2 wave-boundary rows are
// loaded from global. All in-loop loads are asm-pinned with a vmcnt(0) drain
// at iteration top -> one plane of latency always covered, x12 waves/CU TLP.
__global__ __launch_bounds__(BLOCKV, 3) void vol_kernel(const float* __restrict__ p,
                                                        const float* __restrict__ y,
                                                        float* __restrict__ part) {
    const int tid  = threadIdx.x;
    const int wv   = tid >> 6;
    const int lane = tid & 63;
    const int r    = lane >> 4;           // 0..3  row within wave
    const int i16  = lane & 15;           // 0..15 strip within row
    const int w0   = i16 * 12;

    // XCD-bijective swizzle (768 % 8 == 0): consecutive swz = consecutive hb
    // (vertical neighbors sharing boundary rows) on the same XCD's L2.
    const int blk0 = blockIdx.x;
    const int swz  = (blk0 & 7) * (GRIDV / 8) + (blk0 >> 3);
    const int hb   = swz % NHB;
    const int rest = swz / NHB;
    const int dc   = rest % NDC;
    const int b    = rest / NDC;
    const int h0w  = hb * HB + wv * 4;    // wave's base row
    const int h    = h0w + r;
    const int d0   = dc * DT;
    // boundary row this lane fetches: rows r<2 -> h0w-1, r>=2 -> h0w+4 (clamped)
    const int rb   = (r < 2) ? (h0w > 0 ? h0w - 1 : 0)
                             : (h0w + 4 < HDIM ? h0w + 4 : HDIM - 1);

    const long long base  = (long long)(b * DDIM) * PLSTR;
    const long long rowO  = base + (long long)h  * WDIM + w0;  // own row, plane 0
    const long long rowB  = base + (long long)rb * WDIM + w0;  // boundary row, plane 0

    // ---- prologue (plain loads): ym(clamp(d0-1)), yc(d0), bm(d0) ----
    float4 ymY[3], ymP[3], ycY[3], ycP[3], bmY[3], bmP[3];
    {
        const int pm = d0 ? d0 - 1 : 0;
        #pragma unroll
        for (int g = 0; g < 3; ++g) {
            ymY[g] = *(const float4*)(y + rowO + (long long)pm * PLSTR + 4 * g);
            ymP[g] = *(const float4*)(p + rowO + (long long)pm * PLSTR + 4 * g);
            ycY[g] = *(const float4*)(y + rowO + (long long)d0 * PLSTR + 4 * g);
            ycP[g] = *(const float4*)(p + rowO + (long long)d0 * PLSTR + 4 * g);
            bmY[g] = *(const float4*)(y + rowB + (long long)d0 * PLSTR + 4 * g);
            bmP[g] = *(const float4*)(p + rowB + (long long)d0 * PLSTR + 4 * g);
        }
    }
    // ---- issue prefetch for plane d0+1 (always a real plane) ----
    float4 cnY[3], cnP[3], bnY[3], bnP[3];
    {
        const long long po = (long long)(d0 + 1) * PLSTR;
        ALOAD3(cnY[0], cnY[1], cnY[2], y + rowO + po);
        ALOAD3(cnP[0], cnP[1], cnP[2], p + rowO + po);
        ALOAD3(bnY[0], bnY[1], bnY[2], y + rowB + po);
        ALOAD3(bnP[0], bnP[1], bnP[2], p + rowB + po);
    }

    float l1 = 0.f, gd = 0.f;
    const float s2h  = (h == 0 || h == HDIM - 1) ? 1.f : 0.25f;
    const float s2w0 = (i16 == 0)  ? 1.f : 0.25f;
    const float s2w3 = (i16 == 15) ? 1.f : 0.25f;

    #pragma unroll 1
    for (int i = 0; i < DT; ++i) {
        const int e = d0 + i;
        asm volatile("s_waitcnt vmcnt(0)" ::: "memory");   // cn/bn(e+1) ready
        __builtin_amdgcn_sched_barrier(0);

        const float s2d = (e == 0 || e == DDIM - 1) ? 1.f : 0.25f;

        // W-edge scalars from neighbor lanes' registers (garbage at strip 0/15
        // lanes is overridden by the volume-edge select).
        float wlY = __shfl_up (ycY[2].w, 1, 64);
        float wrY = __shfl_down(ycY[0].x, 1, 64);
        float wlP = __shfl_up (ycP[2].w, 1, 64);
        float wrP = __shfl_down(ycP[0].x, 1, 64);
        wlY = (i16 == 0)  ? ycY[0].x : wlY;  wlP = (i16 == 0)  ? ycP[0].x : wlP;
        wrY = (i16 == 15) ? ycY[2].w : wrY;  wrP = (i16 == 15) ? ycP[2].w : wrP;

        #pragma unroll
        for (int g = 0; g < 3; ++g) {
            const float4 ay = ycY[g], ap = ycP[g];
            const float4 my = ymY[g], mp = ymP[g];
            const float4 ny = cnY[g], np2 = cnP[g];

            // L1
            l1 += fabsf(ay.x - ap.x) + fabsf(ay.y - ap.y)
                + fabsf(ay.z - ap.z) + fabsf(ay.w - ap.w);

            // H neighbors: interior rows from lane registers, wave-boundary
            // rows from the fetched boundary row.
            const float4 hmy = sel4(r == 0, bmY[g], shup16(ay));
            const float4 hmp = sel4(r == 0, bmP[g], shup16(ap));
            const float4 hpy = sel4(r == 3, bmY[g], shdn16(ay));
            const float4 hpp = sel4(r == 3, bmP[g], shdn16(ap));
            GTERM(hpy.x - hmy.x, hpp.x - hmp.x, s2h);
            GTERM(hpy.y - hmy.y, hpp.y - hmp.y, s2h);
            GTERM(hpy.z - hmy.z, hpp.z - hmp.z, s2h);
            GTERM(hpy.w - hmy.w, hpp.w - hmp.w, s2h);

            // D axis (register pipeline)
            GTERM(ny.x - my.x, np2.x - mp.x, s2d);
            GTERM(ny.y - my.y, np2.y - mp.y, s2d);
            GTERM(ny.z - my.z, np2.z - mp.z, s2d);
            GTERM(ny.w - my.w, np2.w - mp.w, s2d);
        }
        // W axis: 12 consecutive elements in registers + shfl edges
        {
            const float4 a0 = ycY[0], a1 = ycY[1], a2 = ycY[2];
            const float4 p0 = ycP[0], p1 = ycP[1], p2 = ycP[2];
            GTERM(a0.y - wlY , p0.y - wlP , s2w0);
            GTERM(a0.z - a0.x, p0.z - p0.x, 0.25f);
            GTERM(a0.w - a0.y, p0.w - p0.y, 0.25f);
            GTERM(a1.x - a0.z, p1.x - p0.z, 0.25f);
            GTERM(a1.y - a0.w, p1.y - p0.w, 0.25f);
            GTERM(a1.z - a1.x, p1.z - p1.x, 0.25f);
            GTERM(a1.w - a1.y, p1.w - p1.y, 0.25f);
            GTERM(a2.x - a1.z, p2.x - p1.z, 0.25f);
            GTERM(a2.y - a1.w, p2.y - p1.w, 0.25f);
            GTERM(a2.z - a2.x, p2.z - p2.x, 0.25f);
            GTERM(a2.w - a2.y, p2.w - p2.y, 0.25f);
            GTERM(wrY  - a2.z, wrP  - p2.z, s2w3);
        }

        // shift register D-pipeline and boundary rows
        #pragma unroll
        for (int g = 0; g < 3; ++g) {
            ymY[g] = ycY[g]; ymP[g] = ycP[g];
            ycY[g] = cnY[g]; ycP[g] = cnP[g];
            bmY[g] = bnY[g]; bmP[g] = bnP[g];
        }
        // issue prefetch for plane e+2 (clamped at volume end)
        if (i < DT - 1) {
            int pl = e + 2; if (pl > DDIM - 1) pl = DDIM - 1;
            const long long po = (long long)pl * PLSTR;
            ALOAD3(cnY[0], cnY[1], cnY[2], y + rowO + po);
            ALOAD3(cnP[0], cnP[1], cnP[2], p + rowO + po);
            ALOAD3(bnY[0], bnY[1], bnY[2], y + rowB + po);
            ALOAD3(bnP[0], bnP[1], bnP[2], p + rowB + po);
        }
    }

    // ---- block reduction: 4 waves -> one partial pair per block ----
    __shared__ float red1[4], red2[4];
    #pragma unroll
    for (int off = 32; off > 0; off >>= 1) {
        l1 += __shfl_down(l1, off, 64);
        gd += __shfl_down(gd, off, 64);
    }
    if (lane == 0) { red1[wv] = l1; red2[wv] = gd; }
    __syncthreads();
    if (tid == 0) {
        part[2 * blk0]     = red1[0] + red1[1] + red1[2] + red1[3];
        part[2 * blk0 + 1] = red2[0] + red2[1] + red2[2] + red2[3];
    }
}

// Reduce per-block partials + BCE over the small discriminator tensor.
__global__ __launch_bounds__(BLOCKF) void finalize_kernel(const float* __restrict__ dsc,
                                                          const float* __restrict__ part,
                                                          float* __restrict__ out) {
    float l1 = 0.f, gd = 0.f, s = 0.f;
    for (int i = threadIdx.x; i < GRIDV; i += BLOCKF) {
        l1 += part[2 * i];
        gd += part[2 * i + 1];
    }
    for (int i = threadIdx.x; i < NDSC; i += BLOCKF) {
        const float x = dsc[i];
        // target is zeros: max(x,0) - x*0 + log1p(exp(-|x|))
        s += fmaxf(x, 0.f) + log1pf(expf(-fabsf(x)));
    }
    __shared__ float a[4], c[4], e2[4];
    #pragma unroll
    for (int off = 32; off > 0; off >>= 1) {
        l1 += __shfl_down(l1, off, 64);
        gd += __shfl_down(gd, off, 64);
        s  += __shfl_down(s,  off, 64);
    }
    if ((threadIdx.x & 63) == 0) {
        const int w = threadIdx.x >> 6;
        a[w] = l1; c[w] = gd; e2[w] = s;
    }
    __syncthreads();
    if (threadIdx.x == 0) {
        const float bce = (e2[0] + e2[1] + e2[2] + e2[3]) / (float)NDSC;
        const float l1m = (a[0] + a[1] + a[2] + a[3]) / (float)NTOT;
        const float gdm = (c[0] + c[1] + c[2] + c[3]) / (float)NTOT;
        out[0] = bce + 100.f * (l1m + gdm);
    }
}

extern "C" void kernel_launch(void* const* d_in, const int* in_sizes, int n_in,
                              void* d_out, int out_size, void* d_ws, size_t ws_size,
                              hipStream_t stream) {
    const float* dsc_fake = (const float*)d_in[0];
    const float* predicts = (const float*)d_in[1];
    const float* y_data   = (const float*)d_in[2];
    // d_in[3] (zeros) unused: target==0 makes the -x*target term vanish.
    float* part = (float*)d_ws;   // GRIDV*2 floats, fully overwritten each call
    float* out  = (float*)d_out;

    vol_kernel<<<GRIDV, BLOCKV, 0, stream>>>(predicts, y_data, part);
    finalize_kernel<<<1, BLOCKF, 0, stream>>>(dsc_fake, part, out);
}

// Round 6
// 177.307 us; speedup vs baseline: 1.9987x; 1.9987x over previous
//
#include <hip/hip_runtime.h>
#include <math.h>

namespace {
constexpr int BATCH = 4;
constexpr int DDIM  = 128;
constexpr int HDIM  = 192;
constexpr int WDIM  = 192;
constexpr long long NTOT = (long long)BATCH * DDIM * HDIM * WDIM; // 18,874,368
constexpr int NDSC  = 4 * 1 * 8 * 12 * 12;                        // 4608

constexpr int DT     = 8;               // d planes per block
constexpr int NDC    = DDIM / DT;       // 16
constexpr int HB     = 16;              // h rows per block (4 waves x 4 rows)
constexpr int NHB    = HDIM / HB;       // 12
constexpr int BLOCKV = 256;             // 4 waves
constexpr int GRIDV  = BATCH * NDC * NHB; // 768 = 3 blocks/CU
constexpr int PLSTR  = HDIM * WDIM;     // 36,864 floats per plane
constexpr int BLOCKF = 256;
}

// gd contribution: (|dy|*s - |dp|*s)^2 == s^2 * (|dy|-|dp|)^2, s2 in {1, 0.25}
#define GTERM(dy, dp, s2) { float t0_ = fabsf(dy) - fabsf(dp); gd = fmaf(t0_ * t0_, (s2), gd); }

__device__ __forceinline__ float4 shup16(float4 v) {
    float4 r;
    r.x = __shfl_up(v.x, 16, 64); r.y = __shfl_up(v.y, 16, 64);
    r.z = __shfl_up(v.z, 16, 64); r.w = __shfl_up(v.w, 16, 64);
    return r;
}
__device__ __forceinline__ float4 shdn16(float4 v) {
    float4 r;
    r.x = __shfl_down(v.x, 16, 64); r.y = __shfl_down(v.y, 16, 64);
    r.z = __shfl_down(v.z, 16, 64); r.w = __shfl_down(v.w, 16, 64);
    return r;
}
__device__ __forceinline__ float4 sel4(bool c, float4 a, float4 b) {
    float4 r;
    r.x = c ? a.x : b.x; r.y = c ? a.y : b.y;
    r.z = c ? a.z : b.z; r.w = c ? a.w : b.w;
    return r;
}

// Register-resident stencil, NO inline asm (round-5 lesson: asm-loaded regs
// can be spilled mid-flight). Wave = 4 h-rows x 16 w-strips(12 floats).
// H-neighbors: __shfl +/-16 of center registers (wave-boundary rows loaded,
// L1/L2-hot). W-edges: __shfl +/-1. D: register pipeline + 1-plane-ahead
// prefetch into fresh locals issued BEFORE the compute (no PHIs, compiler
// schedules the waits). Traffic ~12 B/elem; 12 waves/CU.
__global__ __launch_bounds__(BLOCKV, 2) void vol_kernel(const float* __restrict__ p,
                                                        const float* __restrict__ y,
                                                        const float* __restrict__ dsc,
                                                        float* __restrict__ part) {
    const int tid  = threadIdx.x;
    const int wv   = tid >> 6;
    const int lane = tid & 63;
    const int r    = lane >> 4;           // 0..3  row within wave
    const int i16  = lane & 15;           // 0..15 strip within row
    const int w0   = i16 * 12;

    // XCD-bijective swizzle (768 % 8 == 0): consecutive swz = consecutive hb
    // (vertical neighbors sharing boundary rows) on the same XCD's L2.
    const int blk0 = blockIdx.x;
    const int swz  = (blk0 & 7) * (GRIDV / 8) + (blk0 >> 3);
    const int hb   = swz % NHB;
    const int rest = swz / NHB;
    const int dc   = rest % NDC;
    const int b    = rest / NDC;
    const int h0w  = hb * HB + wv * 4;    // wave's base row
    const int h    = h0w + r;
    const int d0   = dc * DT;
    // boundary row this lane fetches: rows r<2 -> h0w-1, r>=2 -> h0w+4 (clamped)
    const int rb   = (r < 2) ? (h0w > 0 ? h0w - 1 : 0)
                             : (h0w + 4 < HDIM ? h0w + 4 : HDIM - 1);

    const long long base = (long long)(b * DDIM) * PLSTR;
    const float* yO = y + base + h  * WDIM + w0;   // own row, plane 0
    const float* pO = p + base + h  * WDIM + w0;
    const float* yB = y + base + rb * WDIM + w0;   // boundary row, plane 0
    const float* pB = p + base + rb * WDIM + w0;

    // ---- prologue: ym(clamp(d0-1)), yc(d0), cn(d0+1) ----
    float4 ymY[3], ymP[3], ycY[3], ycP[3], cnY[3], cnP[3];
    {
        const int pm = d0 ? d0 - 1 : 0;
        #pragma unroll
        for (int g = 0; g < 3; ++g) {
            ymY[g] = *(const float4*)(yO + pm * PLSTR + 4 * g);
            ymP[g] = *(const float4*)(pO + pm * PLSTR + 4 * g);
            ycY[g] = *(const float4*)(yO + d0 * PLSTR + 4 * g);
            ycP[g] = *(const float4*)(pO + d0 * PLSTR + 4 * g);
            cnY[g] = *(const float4*)(yO + (d0 + 1) * PLSTR + 4 * g);
            cnP[g] = *(const float4*)(pO + (d0 + 1) * PLSTR + 4 * g);
        }
    }

    float l1 = 0.f, gd = 0.f;
    const float s2h  = (h == 0 || h == HDIM - 1) ? 1.f : 0.25f;
    const float s2w0 = (i16 == 0)  ? 1.f : 0.25f;
    const float s2w3 = (i16 == 15) ? 1.f : 0.25f;

    #pragma unroll 1
    for (int i = 0; i < DT; ++i) {
        const int e = d0 + i;

        // ---- issue-early (unconditional, fresh locals, no PHIs):
        //      nu = own row plane min(e+2,127); bm = boundary row plane e ----
        const int p2 = (e + 2 < DDIM) ? e + 2 : DDIM - 1;
        float4 nuY[3], nuP[3], bmY[3], bmP[3];
        #pragma unroll
        for (int g = 0; g < 3; ++g) {
            nuY[g] = *(const float4*)(yO + p2 * PLSTR + 4 * g);
            nuP[g] = *(const float4*)(pO + p2 * PLSTR + 4 * g);
            bmY[g] = *(const float4*)(yB + e  * PLSTR + 4 * g);
            bmP[g] = *(const float4*)(pB + e  * PLSTR + 4 * g);
        }

        const float s2d = (e == 0 || e == DDIM - 1) ? 1.f : 0.25f;

        // W-edge scalars from neighbor lanes' registers (strip 0/15 lanes get
        // garbage from the shfl, overridden by the volume-edge select).
        float wlY = __shfl_up (ycY[2].w, 1, 64);
        float wrY = __shfl_down(ycY[0].x, 1, 64);
        float wlP = __shfl_up (ycP[2].w, 1, 64);
        float wrP = __shfl_down(ycP[0].x, 1, 64);
        wlY = (i16 == 0)  ? ycY[0].x : wlY;  wlP = (i16 == 0)  ? ycP[0].x : wlP;
        wrY = (i16 == 15) ? ycY[2].w : wrY;  wrP = (i16 == 15) ? ycP[2].w : wrP;

        #pragma unroll
        for (int g = 0; g < 3; ++g) {
            const float4 ay = ycY[g], ap = ycP[g];
            const float4 my = ymY[g], mp = ymP[g];
            const float4 ny = cnY[g], np2 = cnP[g];

            // L1
            l1 += fabsf(ay.x - ap.x) + fabsf(ay.y - ap.y)
                + fabsf(ay.z - ap.z) + fabsf(ay.w - ap.w);

            // H neighbors: interior rows from lane registers, wave-boundary
            // rows from the fetched boundary row.
            const float4 hmy = sel4(r == 0, bmY[g], shup16(ay));
            const float4 hmp = sel4(r == 0, bmP[g], shup16(ap));
            const float4 hpy = sel4(r == 3, bmY[g], shdn16(ay));
            const float4 hpp = sel4(r == 3, bmP[g], shdn16(ap));
            GTERM(hpy.x - hmy.x, hpp.x - hmp.x, s2h);
            GTERM(hpy.y - hmy.y, hpp.y - hmp.y, s2h);
            GTERM(hpy.z - hmy.z, hpp.z - hmp.z, s2h);
            GTERM(hpy.w - hmy.w, hpp.w - hmp.w, s2h);

            // D axis (register pipeline)
            GTERM(ny.x - my.x, np2.x - mp.x, s2d);
            GTERM(ny.y - my.y, np2.y - mp.y, s2d);
            GTERM(ny.z - my.z, np2.z - mp.z, s2d);
            GTERM(ny.w - my.w, np2.w - mp.w, s2d);
        }
        // W axis: 12 consecutive elements in registers + shfl edges
        {
            const float4 a0 = ycY[0], a1 = ycY[1], a2 = ycY[2];
            const float4 p0 = ycP[0], p1 = ycP[1], p2v = ycP[2];
            GTERM(a0.y - wlY , p0.y - wlP , s2w0);
            GTERM(a0.z - a0.x, p0.z - p0.x, 0.25f);
            GTERM(a0.w - a0.y, p0.w - p0.y, 0.25f);
            GTERM(a1.x - a0.z, p1.x - p0.z, 0.25f);
            GTERM(a1.y - a0.w, p1.y - p0.w, 0.25f);
            GTERM(a1.z - a1.x, p1.z - p1.x, 0.25f);
            GTERM(a1.w - a1.y, p1.w - p1.y, 0.25f);
            GTERM(a2.x - a1.z, p2v.x - p1.z, 0.25f);
            GTERM(a2.y - a1.w, p2v.y - p1.w, 0.25f);
            GTERM(a2.z - a2.x, p2v.z - p2v.x, 0.25f);
            GTERM(a2.w - a2.y, p2v.w - p2v.y, 0.25f);
            GTERM(wrY  - a2.z, wrP  - p2v.z, s2w3);
        }

        // shift register D-pipeline
        #pragma unroll
        for (int g = 0; g < 3; ++g) {
            ymY[g] = ycY[g]; ymP[g] = ycP[g];
            ycY[g] = cnY[g]; ycP[g] = cnP[g];
            cnY[g] = nuY[g]; cnP[g] = nuP[g];
        }
    }

    // ---- BCE partial: blocks 0..17 cover the 4608 dsc logits exactly ----
    float s = 0.f;
    {
        const int gi = blk0 * BLOCKV + tid;
        if (gi < NDSC) {
            const float x = dsc[gi];
            s = fmaxf(x, 0.f) + log1pf(expf(-fabsf(x)));
        }
    }

    // ---- block reduction: 4 waves -> one partial triple per block ----
    __shared__ float red1[4], red2[4], red3[4];
    #pragma unroll
    for (int off = 32; off > 0; off >>= 1) {
        l1 += __shfl_down(l1, off, 64);
        gd += __shfl_down(gd, off, 64);
        s  += __shfl_down(s,  off, 64);
    }
    if (lane == 0) { red1[wv] = l1; red2[wv] = gd; red3[wv] = s; }
    __syncthreads();
    if (tid == 0) {
        part[3 * blk0]     = red1[0] + red1[1] + red1[2] + red1[3];
        part[3 * blk0 + 1] = red2[0] + red2[1] + red2[2] + red2[3];
        part[3 * blk0 + 2] = red3[0] + red3[1] + red3[2] + red3[3];
    }
}

// Reduce per-block partial triples into the scalar loss.
__global__ __launch_bounds__(BLOCKF) void finalize_kernel(const float* __restrict__ part,
                                                          float* __restrict__ out) {
    float l1 = 0.f, gd = 0.f, s = 0.f;
    for (int i = threadIdx.x; i < GRIDV; i += BLOCKF) {
        l1 += part[3 * i];
        gd += part[3 * i + 1];
        s  += part[3 * i + 2];
    }
    __shared__ float a[4], c[4], e2[4];
    #pragma unroll
    for (int off = 32; off > 0; off >>= 1) {
        l1 += __shfl_down(l1, off, 64);
        gd += __shfl_down(gd, off, 64);
        s  += __shfl_down(s,  off, 64);
    }
    if ((threadIdx.x & 63) == 0) {
        const int w = threadIdx.x >> 6;
        a[w] = l1; c[w] = gd; e2[w] = s;
    }
    __syncthreads();
    if (threadIdx.x == 0) {
        const float bce = (e2[0] + e2[1] + e2[2] + e2[3]) / (float)NDSC;
        const float l1m = (a[0] + a[1] + a[2] + a[3]) / (float)NTOT;
        const float gdm = (c[0] + c[1] + c[2] + c[3]) / (float)NTOT;
        out[0] = bce + 100.f * (l1m + gdm);
    }
}

extern "C" void kernel_launch(void* const* d_in, const int* in_sizes, int n_in,
                              void* d_out, int out_size, void* d_ws, size_t ws_size,
                              hipStream_t stream) {
    const float* dsc_fake = (const float*)d_in[0];
    const float* predicts = (const float*)d_in[1];
    const float* y_data   = (const float*)d_in[2];
    // d_in[3] (zeros) unused: target==0 makes the -x*target term vanish.
    float* part = (float*)d_ws;   // GRIDV*3 floats, fully overwritten each call
    float* out  = (float*)d_out;

    vol_kernel<<<GRIDV, BLOCKV, 0, stream>>>(predicts, y_data, dsc_fake, part);
    finalize_kernel<<<1, BLOCKF, 0, stream>>>(part, out);
}